// Round 8
// baseline (1390.079 us; speedup 1.0000x reference)
//
#include <hip/hip_runtime.h>
#include <hip/hip_bf16.h>

// Problem constants (PentachoronCrossAttention)
#define Bsz   8192
#define Vn    5
#define Dm    1792
#define Hn    14
#define HDm   128
#define Mrows (Bsz * Vn)   // 40960
#define N1    (3 * Dm)     // 5376
#define Kd    Dm           // 1792

typedef float f32x4 __attribute__((ext_vector_type(4)));
typedef short bf16x8 __attribute__((ext_vector_type(8)));

__device__ __forceinline__ ushort f2bf(float f) {
    unsigned u = __float_as_uint(f);
    u += 0x7fffu + ((u >> 16) & 1u);   // round-to-nearest-even
    return (ushort)(u >> 16);
}
__device__ __forceinline__ float bf2f(ushort h) {
    return __uint_as_float(((unsigned)h) << 16);
}

#define AS1(p) ((const __attribute__((address_space(1))) void*)(p))
#define AS3(p) ((__attribute__((address_space(3))) void*)(p))

// ---------------- f32 -> bf16 convert ----------------
__global__ void cvt_kernel(const float* __restrict__ in, ushort* __restrict__ out, int n4) {
    int i = blockIdx.x * blockDim.x + threadIdx.x;
    int stride = gridDim.x * blockDim.x;
    for (int idx = i; idx < n4; idx += stride) {
        float4 v = reinterpret_cast<const float4*>(in)[idx];
        ushort4 o;
        o.x = f2bf(v.x); o.y = f2bf(v.y); o.z = f2bf(v.z); o.w = f2bf(v.w);
        reinterpret_cast<ushort4*>(out)[idx] = o;
    }
}

// ---------------- 256x256 8-phase bf16 GEMM, C = A * Bw^T + bias ----------------
// LDS (128 KiB): buf b at b*65536; A k-half kh at +kh*16384; B at +32768+kh*16384.
// Unit = [256 rows][4 slots of 16B], swizzle: phys_slot = log_slot ^ ((row>>1)&3)
//   (round-5 verified: SQ_LDS_BANK_CONFLICT == 0).
// ONE barrier per phase: {reads(p+1); stage; MFMA(p); [odd p: vmcnt(6)]; BAR}.
// vmcnt(6) is TIGHT (ph-p VMC drains exactly the 2 units phase p+1 reads).
// Grouped raster (G=4 bm per group, bm fastest) keeps A in L2, B L3-hot.
// Round-8: TAIL BALANCE - launch grid = 256*floor(ntiles/256); low bids own the
// extra tiles (vt = bid + k*grid), dispatched first -> backfill gives ~ideal
// makespan (13.125 vs 14 rounds GEMM1; 4.375 vs 5 GEMM2).
template<bool OUT_BF16>
__global__ __launch_bounds__(512, 2) void gemm8p(
    const ushort* __restrict__ A,
    const ushort* __restrict__ Bw,
    const float* __restrict__ bias,
    void* __restrict__ Cout,
    int M, int N, int K)
{
    __shared__ __align__(16) char smem[131072];

    const int nTN = N >> 8;
    const int ntiles = (M >> 8) * nTN;
    const int cpx = ntiles >> 3;              // ntiles % 8 == 0 for both launches
    int t = threadIdx.x;
    int lane = t & 63, w = t >> 6;
    int wrow = (w >> 2) * 128;                // 2 waves in M
    int wcol = (w & 3) * 64;                  // 4 waves in N
    int fr = lane & 15, fq = lane >> 4;
    int slotC = ((fq ^ ((fr >> 1) & 3)) << 4);   // swizzled 16B slot (lane-const)
    int aOff = (wrow + fr) * 64 + slotC;
    int bOff = 32768 + (wcol + fr) * 64 + slotC;

    size_t K2 = (size_t)K * 2;
    size_t rowSkip = (size_t)128 * K2;
    int rowL = t >> 2;                                  // 0..127
    int slotSw = (((t & 3) ^ ((t >> 3) & 3)) << 4);     // involution of read swizzle

#define STAGE(SRC, UOFF, KT, KH) { \
    const char* _s = (SRC) + (size_t)(KT) * 128 + (KH) * 64; \
    __builtin_amdgcn_global_load_lds(AS1(_s), AS3(&smem[(UOFF) + t * 16]), 16, 0, 0); \
    __builtin_amdgcn_global_load_lds(AS1(_s + rowSkip), AS3(&smem[(UOFF) + 8192 + t * 16]), 16, 0, 0); }

#define RDA(DST, BUF, KS, M0) { \
    DST[0] = *(const bf16x8*)&smem[(BUF)*65536 + (KS)*16384 + ((M0)+0)*1024 + aOff]; \
    DST[1] = *(const bf16x8*)&smem[(BUF)*65536 + (KS)*16384 + ((M0)+1)*1024 + aOff]; \
    DST[2] = *(const bf16x8*)&smem[(BUF)*65536 + (KS)*16384 + ((M0)+2)*1024 + aOff]; \
    DST[3] = *(const bf16x8*)&smem[(BUF)*65536 + (KS)*16384 + ((M0)+3)*1024 + aOff]; }

#define RDB(DST, BUF, KS) { \
    DST[0] = *(const bf16x8*)&smem[(BUF)*65536 + (KS)*16384 + 0*1024 + bOff]; \
    DST[1] = *(const bf16x8*)&smem[(BUF)*65536 + (KS)*16384 + 1*1024 + bOff]; \
    DST[2] = *(const bf16x8*)&smem[(BUF)*65536 + (KS)*16384 + 2*1024 + bOff]; \
    DST[3] = *(const bf16x8*)&smem[(BUF)*65536 + (KS)*16384 + 3*1024 + bOff]; }

#define MFMAQ(AF, BF, M0) { \
    __builtin_amdgcn_s_setprio(1); \
    _Pragma("unroll") \
    for (int mi = 0; mi < 4; ++mi) { \
      _Pragma("unroll") \
      for (int ni = 0; ni < 4; ++ni) \
        acc[(M0)+mi][ni] = __builtin_amdgcn_mfma_f32_16x16x32_bf16(AF[mi], BF[ni], acc[(M0)+mi][ni], 0, 0, 0); \
    } \
    __builtin_amdgcn_s_setprio(0); }

#define BAR __builtin_amdgcn_s_barrier()
#define VMC(N) asm volatile("s_waitcnt vmcnt(" #N ")" ::: "memory")

    const int NIT = K / 128;     // 14 iterations, 2 K-tiles each

    #pragma unroll 1
    for (int vt = blockIdx.x; vt < ntiles; vt += gridDim.x) {
        // XCD-bijective chunk swizzle on the VIRTUAL tile index
        int swz = (vt & 7) * cpx + (vt >> 3);
        // grouped raster: G=4 bm-rows per group, bm fastest
        int gsz = 4 * nTN;
        int g = swz / gsz, r = swz - g * gsz;
        int bm = g * 4 + (r & 3);
        int bn = r >> 2;

        const char* aSrc = (const char*)A + (size_t)(bm * 256 + rowL) * K2 + slotSw;
        const char* bSrc = (const char*)Bw + (size_t)(bn * 256 + rowL) * K2 + slotSw;

        f32x4 acc[8][4] = {};
        bf16x8 af0[4], af1[4], bf0[4], bf1[4];

        BAR;   // guard: all waves' prev-tile LDS reads done before restaging

        // ---- prologue: stage tile0.k0/k1, tile1.k0 (6 units = 12 loads) ----
        STAGE(aSrc, 0,      0, 0);   // b0.A.k0
        STAGE(bSrc, 32768,  0, 0);   // b0.B.k0
        STAGE(aSrc, 16384,  0, 1);   // b0.A.k1
        STAGE(bSrc, 49152,  0, 1);   // b0.B.k1
        STAGE(aSrc, 65536,  1, 0);   // b1.A.k0
        STAGE(bSrc, 98304,  1, 0);   // b1.B.k0
        VMC(8);                      // oldest 4 loads (= b0.A.k0, b0.B.k0) landed
        BAR;
        // pre-loop reads for MFMA ph1
        RDA(af0, 0, 0, 0); RDB(bf0, 0, 0);

        #pragma unroll 1
        for (int it = 0; it < NIT - 1; ++it) {
            int kt1 = 2 * it + 1, kt2 = 2 * it + 2, kt3 = 2 * it + 3;
            // ph1: read af1<-b0.A.k0 m4-7 | stage b1.A.k1 | MFMA(b0,ks0,m0-3)
            RDA(af1, 0, 0, 4);                 STAGE(aSrc, 81920, kt1, 1);
            MFMAQ(af0, bf0, 0); VMC(6); BAR;
            // ph2: read af0<-b0.A.k1, bf1<-b0.B.k1 | stage b1.B.k1 | MFMA(b0,ks0,m4-7)
            RDA(af0, 0, 1, 0); RDB(bf1, 0, 1); STAGE(bSrc, 114688, kt1, 1);
            MFMAQ(af1, bf0, 4); BAR;
            // ph3: read af1<-b0.A.k1 m4-7 | stage b0.A.k0(T+2) | MFMA(b0,ks1,m0-3)
            RDA(af1, 0, 1, 4);                 STAGE(aSrc, 0, kt2, 0);
            MFMAQ(af0, bf1, 0); VMC(6); BAR;
            // ph4: read af0<-b1.A.k0, bf0<-b1.B.k0 | stage b0.B.k0 | MFMA(b0,ks1,m4-7)
            RDA(af0, 1, 0, 0); RDB(bf0, 1, 0); STAGE(bSrc, 32768, kt2, 0);
            MFMAQ(af1, bf1, 4); BAR;
            // ph5: read af1<-b1.A.k0 m4-7 | stage b0.A.k1 | MFMA(b1,ks0,m0-3)
            RDA(af1, 1, 0, 4);                 STAGE(aSrc, 16384, kt2, 1);
            MFMAQ(af0, bf0, 0); VMC(6); BAR;
            // ph6: read af0<-b1.A.k1, bf1<-b1.B.k1 | stage b0.B.k1 | MFMA(b1,ks0,m4-7)
            RDA(af0, 1, 1, 0); RDB(bf1, 1, 1); STAGE(bSrc, 49152, kt2, 1);
            MFMAQ(af1, bf0, 4); BAR;
            // ph7: read af1<-b1.A.k1 m4-7 | stage b1.A.k0(T+3) | MFMA(b1,ks1,m0-3)
            RDA(af1, 1, 1, 4);                 STAGE(aSrc, 65536, kt3, 0);
            MFMAQ(af0, bf1, 0); VMC(6); BAR;
            // ph8: read af0<-b0.A.k0(T+2), bf0<-b0.B.k0 | stage b1.B.k0 | MFMA(b1,ks1,m4-7)
            RDA(af0, 0, 0, 0); RDB(bf0, 0, 0); STAGE(bSrc, 98304, kt3, 0);
            MFMAQ(af1, bf1, 4); BAR;
        }
        // ---- peeled final iteration: stages ph1,2 only; tighter vmcnt ----
        {
            int kt1 = 2 * NIT - 1;
            RDA(af1, 0, 0, 4);                 STAGE(aSrc, 81920, kt1, 1);
            MFMAQ(af0, bf0, 0); VMC(6); BAR;
            RDA(af0, 0, 1, 0); RDB(bf1, 0, 1); STAGE(bSrc, 114688, kt1, 1);
            MFMAQ(af1, bf0, 4); BAR;
            RDA(af1, 0, 1, 4);
            MFMAQ(af0, bf1, 0); VMC(4); BAR;
            RDA(af0, 1, 0, 0); RDB(bf0, 1, 0);
            MFMAQ(af1, bf1, 4); BAR;
            RDA(af1, 1, 0, 4);
            MFMAQ(af0, bf0, 0); VMC(0); BAR;
            RDA(af0, 1, 1, 0); RDB(bf1, 1, 1);
            MFMAQ(af1, bf0, 4); BAR;
            RDA(af1, 1, 1, 4);
            MFMAQ(af0, bf1, 0); BAR;
            MFMAQ(af1, bf1, 4);
        }

        // ---- epilogue: C/D layout col=lane&15, row=(lane>>4)*4+reg ----
        float*  Cf = (float*)Cout;
        ushort* Cb = (ushort*)Cout;
        #pragma unroll
        for (int mi = 0; mi < 8; ++mi) {
            int row0 = bm * 256 + wrow + mi * 16 + fq * 4;
            #pragma unroll
            for (int ni = 0; ni < 4; ++ni) {
                int col = bn * 256 + wcol + ni * 16 + fr;
                float bv = bias[col];
                #pragma unroll
                for (int rr = 0; rr < 4; ++rr) {
                    float val = acc[mi][ni][rr] + bv;
                    size_t off = (size_t)(row0 + rr) * N + col;
                    if (OUT_BF16) Cb[off] = f2bf(val);
                    else          Cf[off] = val;
                }
            }
        }
    }

#undef STAGE
#undef RDA
#undef RDB
#undef MFMAQ
#undef BAR
#undef VMC
}

// ---------------- tiny 5x5 masked attention, one wave per (b,h) ----------------
__global__ __launch_bounds__(256) void attn_kernel(
    const ushort* __restrict__ qkv,
    const int* __restrict__ adj,
    ushort* __restrict__ outp)
{
    int gw = blockIdx.x * 4 + (threadIdx.x >> 6);
    int lane = threadIdx.x & 63;
    int b = gw / Hn;
    int h = gw - b * Hn;

    const ushort* base = qkv + (size_t)b * 5 * N1 + h * HDm + 2 * lane;
    float q[5][2], k[5][2], v[5][2];
    #pragma unroll
    for (int i = 0; i < 5; ++i) {
        ushort2 qq = *reinterpret_cast<const ushort2*>(base + (size_t)i * N1);
        ushort2 kk = *reinterpret_cast<const ushort2*>(base + (size_t)i * N1 + Dm);
        ushort2 vv = *reinterpret_cast<const ushort2*>(base + (size_t)i * N1 + 2 * Dm);
        q[i][0] = bf2f(qq.x); q[i][1] = bf2f(qq.y);
        k[i][0] = bf2f(kk.x); k[i][1] = bf2f(kk.y);
        v[i][0] = bf2f(vv.x); v[i][1] = bf2f(vv.y);
    }

    float s[5][5];
    #pragma unroll
    for (int i = 0; i < 5; ++i)
        #pragma unroll
        for (int j = 0; j < 5; ++j) {
            float p = q[i][0] * k[j][0] + q[i][1] * k[j][1];
            #pragma unroll
            for (int off = 32; off > 0; off >>= 1)
                p += __shfl_xor(p, off);
            s[i][j] = p;
        }

    const float scale = 0.08838834764831845f;  // 1/sqrt(128)
    float aw[5][5];
    #pragma unroll
    for (int i = 0; i < 5; ++i) {
        float sv[5];
        float mx = -3.0e38f;
        #pragma unroll
        for (int j = 0; j < 5; ++j) {
            float val = s[i][j] * scale + (adj[i * 5 + j] == 0 ? -1e30f : 0.0f);
            sv[j] = val;
            mx = fmaxf(mx, val);
        }
        float denom = 0.0f;
        #pragma unroll
        for (int j = 0; j < 5; ++j) { sv[j] = __expf(sv[j] - mx); denom += sv[j]; }
        float rd = 1.0f / denom;
        #pragma unroll
        for (int j = 0; j < 5; ++j) aw[i][j] = sv[j] * rd;
    }

    ushort* ob = outp + (size_t)b * 5 * Dm + h * HDm + 2 * lane;
    #pragma unroll
    for (int i = 0; i < 5; ++i) {
        float o0 = 0.0f, o1 = 0.0f;
        #pragma unroll
        for (int j = 0; j < 5; ++j) { o0 += aw[i][j] * v[j][0]; o1 += aw[i][j] * v[j][1]; }
        ushort2 ov; ov.x = f2bf(o0); ov.y = f2bf(o1);
        *reinterpret_cast<ushort2*>(ob + (size_t)i * Dm) = ov;
    }
}

extern "C" void kernel_launch(void* const* d_in, const int* in_sizes, int n_in,
                              void* d_out, int out_size, void* d_ws, size_t ws_size,
                              hipStream_t stream) {
    const float* vertices  = (const float*)d_in[0];
    const int*   adjacency = (const int*)  d_in[1];
    const float* w1        = (const float*)d_in[2];
    const float* b1        = (const float*)d_in[3];
    const float* w2        = (const float*)d_in[4];
    const float* b2        = (const float*)d_in[5];
    float* out = (float*)d_out;

    char* ws = (char*)d_ws;
    const size_t vertBytes = (size_t)Mrows * Kd * 2;
    const size_t qkvBytes  = (size_t)Mrows * N1 * 2;
    const size_t w1Bytes   = (size_t)N1 * Kd * 2;
    const size_t w2Bytes   = (size_t)Dm * Dm * 2;
    const size_t needed    = vertBytes + qkvBytes + w1Bytes + w2Bytes;
    if (ws_size < needed) return;

    ushort* vert_bf = (ushort*)ws;
    ushort* qkv_bf  = (ushort*)(ws + vertBytes);
    ushort* w1_bf   = (ushort*)(ws + vertBytes + qkvBytes);
    ushort* w2_bf   = (ushort*)(ws + vertBytes + qkvBytes + w1Bytes);

    cvt_kernel<<<2048, 256, 0, stream>>>(vertices, vert_bf, Mrows * Kd / 4);
    cvt_kernel<<<512,  256, 0, stream>>>(w1, w1_bf, N1 * Kd / 4);
    cvt_kernel<<<256,  256, 0, stream>>>(w2, w2_bf, Dm * Dm / 4);

    // GEMM1: 3360 tiles on grid 3328 (13 rounds; bids 0-31 take 2 tiles)
    gemm8p<true><<<3328, 512, 0, stream>>>(
        vert_bf, w1_bf, b1, qkv_bf, Mrows, N1, Kd);

    // attention (bf16 attn_out into vert_bf region)
    attn_kernel<<<Bsz * Hn / 4, 256, 0, stream>>>(qkv_bf, adjacency, vert_bf);

    // GEMM2: 1120 tiles on grid 1024 (bids 0-95 take 2 tiles)
    gemm8p<false><<<1024, 512, 0, stream>>>(
        vert_bf, w2_bf, b2, out, Mrows, Dm, Kd);
}

// Round 9
// 1203.655 us; speedup vs baseline: 1.1549x; 1.1549x over previous
//
#include <hip/hip_runtime.h>
#include <hip/hip_bf16.h>

// Problem constants (PentachoronCrossAttention)
#define Bsz   8192
#define Vn    5
#define Dm    1792
#define Hn    14
#define HDm   128
#define Mrows (Bsz * Vn)   // 40960
#define N1    (3 * Dm)     // 5376
#define Kd    Dm           // 1792

typedef float f32x4 __attribute__((ext_vector_type(4)));
typedef short bf16x8 __attribute__((ext_vector_type(8)));

__device__ __forceinline__ ushort f2bf(float f) {
    unsigned u = __float_as_uint(f);
    u += 0x7fffu + ((u >> 16) & 1u);   // round-to-nearest-even
    return (ushort)(u >> 16);
}
__device__ __forceinline__ float bf2f(ushort h) {
    return __uint_as_float(((unsigned)h) << 16);
}

#define AS1(p) ((const __attribute__((address_space(1))) void*)(p))
#define AS3(p) ((__attribute__((address_space(3))) void*)(p))

// ---------------- f32 -> bf16 convert ----------------
__global__ void cvt_kernel(const float* __restrict__ in, ushort* __restrict__ out, int n4) {
    int i = blockIdx.x * blockDim.x + threadIdx.x;
    int stride = gridDim.x * blockDim.x;
    for (int idx = i; idx < n4; idx += stride) {
        float4 v = reinterpret_cast<const float4*>(in)[idx];
        ushort4 o;
        o.x = f2bf(v.x); o.y = f2bf(v.y); o.z = f2bf(v.z); o.w = f2bf(v.w);
        reinterpret_cast<ushort4*>(out)[idx] = o;
    }
}

// ---------------- 256x256 8-phase bf16 GEMM, C = A * Bw^T + bias ----------------
// LDS (128 KiB): buf b at b*65536; A k-half kh at +kh*16384; B at +32768+kh*16384.
// Unit = [256 rows][4 slots of 16B], swizzle: phys_slot = log_slot ^ ((row>>1)&3)
//   (round-5 verified: SQ_LDS_BANK_CONFLICT == 0).
// ONE barrier per phase. Round-9: MFMA-FIRST phase order:
//   {MFMAQ(frags read last phase); reads(p+1); stage; [odd p: vmcnt(6)]; BAR}
// so waves enter the MFMA pipe at phase start and ds_reads drain in its shadow
// (round-8 analysis: read-issue-first serialized LDS (565cy) + MFMA (620cy)).
// WAR map unchanged: every stage >= 2 barriers after its unit's last read-issue.
// vmcnt(6) is TIGHT (drains exactly the 2 units the next phase's MFMA consumes
// one phase later). Grouped raster keeps A in L2, B L3-hot (round-7, verified
// FETCH 1.6->0.79 GB). Non-persistent grid (round-8 persistence regressed).
template<bool OUT_BF16>
__global__ __launch_bounds__(512, 2) void gemm8p(
    const ushort* __restrict__ A,
    const ushort* __restrict__ Bw,
    const float* __restrict__ bias,
    void* __restrict__ Cout,
    int M, int N, int K)
{
    __shared__ __align__(16) char smem[131072];

    const int nTN = N >> 8;
    int bid = blockIdx.x;
    int cpx = gridDim.x >> 3;                 // grid % 8 == 0 for both launches
    int swz = (bid & 7) * cpx + (bid >> 3);   // XCD-bijective chunk swizzle
    // grouped raster: G=4 bm-rows per group, bm fastest
    int gsz = 4 * nTN;
    int g = swz / gsz, r = swz - g * gsz;
    int bm = g * 4 + (r & 3);
    int bn = r >> 2;

    int t = threadIdx.x;
    int lane = t & 63, w = t >> 6;
    int wrow = (w >> 2) * 128;                // 2 waves in M
    int wcol = (w & 3) * 64;                  // 4 waves in N
    int fr = lane & 15, fq = lane >> 4;
    int slotC = ((fq ^ ((fr >> 1) & 3)) << 4);   // swizzled 16B slot (lane-const)
    int aOff = (wrow + fr) * 64 + slotC;
    int bOff = 32768 + (wcol + fr) * 64 + slotC;

    // staging source (pre-swizzled per-lane global address; LDS dest stays linear)
    size_t K2 = (size_t)K * 2;
    size_t rowSkip = (size_t)128 * K2;
    int rowL = t >> 2;                                  // 0..127
    int slotSw = (((t & 3) ^ ((t >> 3) & 3)) << 4);     // involution of read swizzle
    const char* aSrc = (const char*)A + (size_t)(bm * 256 + rowL) * K2 + slotSw;
    const char* bSrc = (const char*)Bw + (size_t)(bn * 256 + rowL) * K2 + slotSw;

    f32x4 acc[8][4] = {};
    bf16x8 af0[4], af1[4], bf0[4], bf1[4];

#define STAGE(SRC, UOFF, KT, KH) { \
    const char* _s = (SRC) + (size_t)(KT) * 128 + (KH) * 64; \
    __builtin_amdgcn_global_load_lds(AS1(_s), AS3(&smem[(UOFF) + t * 16]), 16, 0, 0); \
    __builtin_amdgcn_global_load_lds(AS1(_s + rowSkip), AS3(&smem[(UOFF) + 8192 + t * 16]), 16, 0, 0); }

#define RDA(DST, BUF, KS, M0) { \
    DST[0] = *(const bf16x8*)&smem[(BUF)*65536 + (KS)*16384 + ((M0)+0)*1024 + aOff]; \
    DST[1] = *(const bf16x8*)&smem[(BUF)*65536 + (KS)*16384 + ((M0)+1)*1024 + aOff]; \
    DST[2] = *(const bf16x8*)&smem[(BUF)*65536 + (KS)*16384 + ((M0)+2)*1024 + aOff]; \
    DST[3] = *(const bf16x8*)&smem[(BUF)*65536 + (KS)*16384 + ((M0)+3)*1024 + aOff]; }

#define RDB(DST, BUF, KS) { \
    DST[0] = *(const bf16x8*)&smem[(BUF)*65536 + (KS)*16384 + 0*1024 + bOff]; \
    DST[1] = *(const bf16x8*)&smem[(BUF)*65536 + (KS)*16384 + 1*1024 + bOff]; \
    DST[2] = *(const bf16x8*)&smem[(BUF)*65536 + (KS)*16384 + 2*1024 + bOff]; \
    DST[3] = *(const bf16x8*)&smem[(BUF)*65536 + (KS)*16384 + 3*1024 + bOff]; }

#define MFMAQ(AF, BF, M0) { \
    __builtin_amdgcn_s_setprio(1); \
    _Pragma("unroll") \
    for (int mi = 0; mi < 4; ++mi) { \
      _Pragma("unroll") \
      for (int ni = 0; ni < 4; ++ni) \
        acc[(M0)+mi][ni] = __builtin_amdgcn_mfma_f32_16x16x32_bf16(AF[mi], BF[ni], acc[(M0)+mi][ni], 0, 0, 0); \
    } \
    __builtin_amdgcn_s_setprio(0); }

#define BAR __builtin_amdgcn_s_barrier()
#define VMC(N) asm volatile("s_waitcnt vmcnt(" #N ")" ::: "memory")

    // ---- prologue: stage tile0.k0/k1, tile1.k0 (6 units = 12 loads) ----
    STAGE(aSrc, 0,      0, 0);   // b0.A.k0
    STAGE(bSrc, 32768,  0, 0);   // b0.B.k0
    STAGE(aSrc, 16384,  0, 1);   // b0.A.k1
    STAGE(bSrc, 49152,  0, 1);   // b0.B.k1
    STAGE(aSrc, 65536,  1, 0);   // b1.A.k0
    STAGE(bSrc, 98304,  1, 0);   // b1.B.k0
    VMC(8);                      // oldest 4 loads (= b0.A.k0, b0.B.k0) landed
    BAR;
    // pre-loop reads for MFMA ph1
    RDA(af0, 0, 0, 0); RDB(bf0, 0, 0);

    const int NIT = K / 128;     // 14 iterations, 2 K-tiles each
    #pragma unroll 1
    for (int it = 0; it < NIT - 1; ++it) {
        int kt1 = 2 * it + 1, kt2 = 2 * it + 2, kt3 = 2 * it + 3;
        // ph1: MFMA(b0,ks0,m0-3) | read af1<-b0.A.k0 m4-7 | stage b1.A.k1
        MFMAQ(af0, bf0, 0); RDA(af1, 0, 0, 4);                 STAGE(aSrc, 81920, kt1, 1);
        VMC(6); BAR;
        // ph2: MFMA(b0,ks0,m4-7) | read af0<-b0.A.k1, bf1<-b0.B.k1 | stage b1.B.k1
        MFMAQ(af1, bf0, 4); RDA(af0, 0, 1, 0); RDB(bf1, 0, 1); STAGE(bSrc, 114688, kt1, 1);
        BAR;
        // ph3: MFMA(b0,ks1,m0-3) | read af1<-b0.A.k1 m4-7 | stage b0.A.k0(T+2)
        MFMAQ(af0, bf1, 0); RDA(af1, 0, 1, 4);                 STAGE(aSrc, 0, kt2, 0);
        VMC(6); BAR;
        // ph4: MFMA(b0,ks1,m4-7) | read af0<-b1.A.k0, bf0<-b1.B.k0 | stage b0.B.k0
        MFMAQ(af1, bf1, 4); RDA(af0, 1, 0, 0); RDB(bf0, 1, 0); STAGE(bSrc, 32768, kt2, 0);
        BAR;
        // ph5: MFMA(b1,ks0,m0-3) | read af1<-b1.A.k0 m4-7 | stage b0.A.k1
        MFMAQ(af0, bf0, 0); RDA(af1, 1, 0, 4);                 STAGE(aSrc, 16384, kt2, 1);
        VMC(6); BAR;
        // ph6: MFMA(b1,ks0,m4-7) | read af0<-b1.A.k1, bf1<-b1.B.k1 | stage b0.B.k1
        MFMAQ(af1, bf0, 4); RDA(af0, 1, 1, 0); RDB(bf1, 1, 1); STAGE(bSrc, 49152, kt2, 1);
        BAR;
        // ph7: MFMA(b1,ks1,m0-3) | read af1<-b1.A.k1 m4-7 | stage b1.A.k0(T+3)
        MFMAQ(af0, bf1, 0); RDA(af1, 1, 1, 4);                 STAGE(aSrc, 65536, kt3, 0);
        VMC(6); BAR;
        // ph8: MFMA(b1,ks1,m4-7) | read af0<-b0.A.k0(T+2), bf0<-b0.B.k0 | stage b1.B.k0
        MFMAQ(af1, bf1, 4); RDA(af0, 0, 0, 0); RDB(bf0, 0, 0); STAGE(bSrc, 98304, kt3, 0);
        BAR;
    }
    // ---- peeled final iteration: stages ph1,2 only; tighter vmcnt ----
    {
        int kt1 = 2 * NIT - 1;
        MFMAQ(af0, bf0, 0); RDA(af1, 0, 0, 4);                 STAGE(aSrc, 81920, kt1, 1);
        VMC(6); BAR;
        MFMAQ(af1, bf0, 4); RDA(af0, 0, 1, 0); RDB(bf1, 0, 1); STAGE(bSrc, 114688, kt1, 1);
        BAR;
        MFMAQ(af0, bf1, 0); RDA(af1, 0, 1, 4);
        VMC(4); BAR;
        MFMAQ(af1, bf1, 4); RDA(af0, 1, 0, 0); RDB(bf0, 1, 0);
        BAR;
        MFMAQ(af0, bf0, 0); RDA(af1, 1, 0, 4);
        VMC(0); BAR;
        MFMAQ(af1, bf0, 4); RDA(af0, 1, 1, 0); RDB(bf1, 1, 1);
        BAR;
        MFMAQ(af0, bf1, 0); RDA(af1, 1, 1, 4);
        BAR;
        MFMAQ(af1, bf1, 4);
    }

#undef STAGE
#undef RDA
#undef RDB
#undef MFMAQ
#undef BAR
#undef VMC

    // ---- epilogue: C/D layout col=lane&15, row=(lane>>4)*4+reg ----
    float*  Cf = (float*)Cout;
    ushort* Cb = (ushort*)Cout;
    #pragma unroll
    for (int mi = 0; mi < 8; ++mi) {
        int row0 = bm * 256 + wrow + mi * 16 + fq * 4;
        #pragma unroll
        for (int ni = 0; ni < 4; ++ni) {
            int col = bn * 256 + wcol + ni * 16 + fr;
            float bv = bias[col];
            #pragma unroll
            for (int rr = 0; rr < 4; ++rr) {
                float val = acc[mi][ni][rr] + bv;
                size_t off = (size_t)(row0 + rr) * N + col;
                if (OUT_BF16) Cb[off] = f2bf(val);
                else          Cf[off] = val;
            }
        }
    }
}

// ---------------- tiny 5x5 masked attention, one wave per (b,h) ----------------
__global__ __launch_bounds__(256) void attn_kernel(
    const ushort* __restrict__ qkv,
    const int* __restrict__ adj,
    ushort* __restrict__ outp)
{
    int gw = blockIdx.x * 4 + (threadIdx.x >> 6);
    int lane = threadIdx.x & 63;
    int b = gw / Hn;
    int h = gw - b * Hn;

    const ushort* base = qkv + (size_t)b * 5 * N1 + h * HDm + 2 * lane;
    float q[5][2], k[5][2], v[5][2];
    #pragma unroll
    for (int i = 0; i < 5; ++i) {
        ushort2 qq = *reinterpret_cast<const ushort2*>(base + (size_t)i * N1);
        ushort2 kk = *reinterpret_cast<const ushort2*>(base + (size_t)i * N1 + Dm);
        ushort2 vv = *reinterpret_cast<const ushort2*>(base + (size_t)i * N1 + 2 * Dm);
        q[i][0] = bf2f(qq.x); q[i][1] = bf2f(qq.y);
        k[i][0] = bf2f(kk.x); k[i][1] = bf2f(kk.y);
        v[i][0] = bf2f(vv.x); v[i][1] = bf2f(vv.y);
    }

    float s[5][5];
    #pragma unroll
    for (int i = 0; i < 5; ++i)
        #pragma unroll
        for (int j = 0; j < 5; ++j) {
            float p = q[i][0] * k[j][0] + q[i][1] * k[j][1];
            #pragma unroll
            for (int off = 32; off > 0; off >>= 1)
                p += __shfl_xor(p, off);
            s[i][j] = p;
        }

    const float scale = 0.08838834764831845f;  // 1/sqrt(128)
    float aw[5][5];
    #pragma unroll
    for (int i = 0; i < 5; ++i) {
        float sv[5];
        float mx = -3.0e38f;
        #pragma unroll
        for (int j = 0; j < 5; ++j) {
            float val = s[i][j] * scale + (adj[i * 5 + j] == 0 ? -1e30f : 0.0f);
            sv[j] = val;
            mx = fmaxf(mx, val);
        }
        float denom = 0.0f;
        #pragma unroll
        for (int j = 0; j < 5; ++j) { sv[j] = __expf(sv[j] - mx); denom += sv[j]; }
        float rd = 1.0f / denom;
        #pragma unroll
        for (int j = 0; j < 5; ++j) aw[i][j] = sv[j] * rd;
    }

    ushort* ob = outp + (size_t)b * 5 * Dm + h * HDm + 2 * lane;
    #pragma unroll
    for (int i = 0; i < 5; ++i) {
        float o0 = 0.0f, o1 = 0.0f;
        #pragma unroll
        for (int j = 0; j < 5; ++j) { o0 += aw[i][j] * v[j][0]; o1 += aw[i][j] * v[j][1]; }
        ushort2 ov; ov.x = f2bf(o0); ov.y = f2bf(o1);
        *reinterpret_cast<ushort2*>(ob + (size_t)i * Dm) = ov;
    }
}

extern "C" void kernel_launch(void* const* d_in, const int* in_sizes, int n_in,
                              void* d_out, int out_size, void* d_ws, size_t ws_size,
                              hipStream_t stream) {
    const float* vertices  = (const float*)d_in[0];
    const int*   adjacency = (const int*)  d_in[1];
    const float* w1        = (const float*)d_in[2];
    const float* b1        = (const float*)d_in[3];
    const float* w2        = (const float*)d_in[4];
    const float* b2        = (const float*)d_in[5];
    float* out = (float*)d_out;

    char* ws = (char*)d_ws;
    const size_t vertBytes = (size_t)Mrows * Kd * 2;
    const size_t qkvBytes  = (size_t)Mrows * N1 * 2;
    const size_t w1Bytes   = (size_t)N1 * Kd * 2;
    const size_t w2Bytes   = (size_t)Dm * Dm * 2;
    const size_t needed    = vertBytes + qkvBytes + w1Bytes + w2Bytes;
    if (ws_size < needed) return;

    ushort* vert_bf = (ushort*)ws;
    ushort* qkv_bf  = (ushort*)(ws + vertBytes);
    ushort* w1_bf   = (ushort*)(ws + vertBytes + qkvBytes);
    ushort* w2_bf   = (ushort*)(ws + vertBytes + qkvBytes + w1Bytes);

    cvt_kernel<<<2048, 256, 0, stream>>>(vertices, vert_bf, Mrows * Kd / 4);
    cvt_kernel<<<512,  256, 0, stream>>>(w1, w1_bf, N1 * Kd / 4);
    cvt_kernel<<<256,  256, 0, stream>>>(w2, w2_bf, Dm * Dm / 4);

    // GEMM1: qkv = vertices @ W1^T + b1   (bf16 out). grid 160*21=3360 (%8==0)
    gemm8p<true><<<(Mrows / 256) * (N1 / 256), 512, 0, stream>>>(
        vert_bf, w1_bf, b1, qkv_bf, Mrows, N1, Kd);

    // attention (bf16 attn_out into vert_bf region)
    attn_kernel<<<Bsz * Hn / 4, 256, 0, stream>>>(qkv_bf, adjacency, vert_bf);

    // GEMM2: out = attn_out @ W2^T + b2   (f32 out). grid 160*7=1120 (%8==0)
    gemm8p<false><<<(Mrows / 256) * (Dm / 256), 512, 0, stream>>>(
        vert_bf, w2_bf, b2, out, Mrows, Dm, Kd);
}